// Round 1
// baseline (3172.786 us; speedup 1.0000x reference)
//
#include <hip/hip_runtime.h>

#define H 128
#define D 2
#define T_OBS 20
#define BATCH 16384
#define PRED 30
#define TILE 32      // batch rows per block
#define NTH 256      // 4 waves
#define HS 132       // padded LDS row stride (16B-aligned, bank-spread)
#define LN_EPS 1e-5f

__device__ __forceinline__ float fast_rcp(float x) { return __builtin_amdgcn_rcpf(x); }
__device__ __forceinline__ float sigmoid_f(float x) { return fast_rcp(1.f + __expf(-x)); }
__device__ __forceinline__ float tanh_f(float x) { return 1.f - 2.f * fast_rcp(__expf(2.f * x) + 1.f); }

// ---------------------------------------------------------------------------
// Pack Whh [4H][H] (gate-major rows) -> k-major float4 per (k,u):
//   P[chain][k][u] = { Whh[0H+u][k], Whh[1H+u][k], Whh[2H+u][k], Whh[3H+u][k] }
// so the main loop's weight load is one coalesced 16B vector per (k, u).
// ---------------------------------------------------------------------------
__global__ void pack_whh_kernel(const float* __restrict__ pe, const float* __restrict__ se,
                                const float* __restrict__ sd, const float* __restrict__ pd,
                                float4* __restrict__ out)
{
    int idx = blockIdx.x * blockDim.x + threadIdx.x;
    if (idx >= 4 * H * H) return;
    int chain = idx >> 14;            // / (128*128)
    int k = (idx >> 7) & (H - 1);
    int u = idx & (H - 1);
    const float* W = (chain == 0) ? pe : (chain == 1) ? se : (chain == 2) ? sd : pd;
    float4 v;
    v.x = W[(0 * H + u) * H + k];
    v.y = W[(1 * H + u) * H + k];
    v.z = W[(2 * H + u) * H + k];
    v.w = W[(3 * H + u) * H + k];
    out[idx] = v;
}

__device__ __forceinline__ void fma4(float4& acc, const float4 w, const float h)
{
    acc.x = fmaf(w.x, h, acc.x);
    acc.y = fmaf(w.y, h, acc.y);
    acc.z = fmaf(w.z, h, acc.z);
    acc.w = fmaf(w.w, h, acc.w);
}

// Per-unit input weights (Wih columns, gate-major) and summed bias.
__device__ __forceinline__ void load_wx(const float* __restrict__ Wih,
                                        const float* __restrict__ bih,
                                        const float* __restrict__ bhh, int u,
                                        float4& wd0, float4& wd1, float4& bs)
{
    wd0 = make_float4(Wih[(0 * H + u) * D], Wih[(1 * H + u) * D],
                      Wih[(2 * H + u) * D], Wih[(3 * H + u) * D]);
    wd1 = make_float4(Wih[(0 * H + u) * D + 1], Wih[(1 * H + u) * D + 1],
                      Wih[(2 * H + u) * D + 1], Wih[(3 * H + u) * D + 1]);
    bs = make_float4(bih[0 * H + u] + bhh[0 * H + u], bih[1 * H + u] + bhh[1 * H + u],
                     bih[2 * H + u] + bhh[2 * H + u], bih[3 * H + u] + bhh[3 * H + u]);
}

// One LSTM cell step for this thread's (u0,u1) x 8 rows. hbuf updated in place.
__device__ __forceinline__ void lstm_step(
    float* __restrict__ hbuf, const float* __restrict__ xbuf,
    const float4* __restrict__ wP,
    const float4 wd0_0, const float4 wd1_0, const float4 bs_0,
    const float4 wd0_1, const float4 wd1_1, const float4 bs_1,
    const int rbase, const int u0, const int u1,
    float (&c0)[8], float (&c1)[8])
{
    float4 acc0[8], acc1[8];
#pragma unroll
    for (int j = 0; j < 8; j++) {
        const float x0 = xbuf[(rbase + j) * D + 0];
        const float x1 = xbuf[(rbase + j) * D + 1];
        float4 a = bs_0;
        fma4(a, wd0_0, x0); fma4(a, wd1_0, x1);
        acc0[j] = a;
        float4 b = bs_1;
        fma4(b, wd0_1, x0); fma4(b, wd1_1, x1);
        acc1[j] = b;
    }
#pragma unroll 2
    for (int k = 0; k < H; k += 4) {
        float4 w0[4], w1[4];
#pragma unroll
        for (int i = 0; i < 4; i++) {
            w0[i] = wP[(k + i) * H + u0];
            w1[i] = wP[(k + i) * H + u1];
        }
#pragma unroll
        for (int j = 0; j < 8; j++) {
            const float4 hv = *(const float4*)(hbuf + (rbase + j) * HS + k);  // LDS broadcast
            fma4(acc0[j], w0[0], hv.x); fma4(acc0[j], w0[1], hv.y);
            fma4(acc0[j], w0[2], hv.z); fma4(acc0[j], w0[3], hv.w);
            fma4(acc1[j], w1[0], hv.x); fma4(acc1[j], w1[1], hv.y);
            fma4(acc1[j], w1[2], hv.z); fma4(acc1[j], w1[3], hv.w);
        }
    }
    __syncthreads();   // all reads of hbuf done before overwrite
#pragma unroll
    for (int j = 0; j < 8; j++) {
        {
            const float ig = sigmoid_f(acc0[j].x);
            const float fg = sigmoid_f(acc0[j].y);
            const float gg = tanh_f(acc0[j].z);
            const float og = sigmoid_f(acc0[j].w);
            const float c = fmaf(fg, c0[j], ig * gg);
            c0[j] = c;
            hbuf[(rbase + j) * HS + u0] = og * tanh_f(c);
        }
        {
            const float ig = sigmoid_f(acc1[j].x);
            const float fg = sigmoid_f(acc1[j].y);
            const float gg = tanh_f(acc1[j].z);
            const float og = sigmoid_f(acc1[j].w);
            const float c = fmaf(fg, c1[j], ig * gg);
            c1[j] = c;
            hbuf[(rbase + j) * HS + u1] = og * tanh_f(c);
        }
    }
    __syncthreads();   // new h visible
}

__device__ void encode_chain(const float* __restrict__ seq, const float4* __restrict__ wP,
                             const float* __restrict__ Wih, const float* __restrict__ bih,
                             const float* __restrict__ bhh,
                             float* __restrict__ hbuf, float* __restrict__ xbuf,
                             const int tid, const int row0, const int rbase,
                             const int u0, const int u1,
                             float (&c0)[8], float (&c1)[8])
{
    for (int idx = tid; idx < TILE * H; idx += NTH)
        hbuf[(idx >> 7) * HS + (idx & (H - 1))] = 0.f;
#pragma unroll
    for (int j = 0; j < 8; j++) { c0[j] = 0.f; c1[j] = 0.f; }
    float4 wd0_0, wd1_0, bs_0, wd0_1, wd1_1, bs_1;
    load_wx(Wih, bih, bhh, u0, wd0_0, wd1_0, bs_0);
    load_wx(Wih, bih, bhh, u1, wd0_1, wd1_1, bs_1);
    for (int t = 0; t < T_OBS; t++) {
        if (tid < TILE * D) xbuf[tid] = seq[t * BATCH * D + row0 * D + tid];
        __syncthreads();
        lstm_step(hbuf, xbuf, wP, wd0_0, wd1_0, bs_0, wd0_1, wd1_1, bs_1,
                  rbase, u0, u1, c0, c1);
    }
}

// LayerNorm over H=128 for 32 rows; 8 threads per row, shfl reduce.
__device__ __forceinline__ void layernorm_lds(float* __restrict__ arr,
                                              const float* __restrict__ g,
                                              const float* __restrict__ b, const int tid)
{
    const int r = tid >> 3, q = tid & 7;
    float* row = arr + r * HS + q * 16;
    float s = 0.f, s2 = 0.f;
#pragma unroll
    for (int i = 0; i < 16; i++) { const float v = row[i]; s += v; s2 = fmaf(v, v, s2); }
#pragma unroll
    for (int m = 1; m < 8; m <<= 1) { s += __shfl_xor(s, m, 64); s2 += __shfl_xor(s2, m, 64); }
    const float mean = s * (1.f / H);
    const float var = s2 * (1.f / H) - mean * mean;
    const float inv = rsqrtf(var + LN_EPS);
    const float* gg = g + q * 16;
    const float* bb = b + q * 16;
#pragma unroll
    for (int i = 0; i < 16; i++) row[i] = fmaf((row[i] - mean) * inv, gg[i], bb[i]);
}

// cs = h @ Wfc^T + bfc  (Wfc is [D][H]); write to LDS xout and global gout.
__device__ __forceinline__ void fc_out(const float* __restrict__ hbuf,
                                       const float* __restrict__ Wfc,
                                       const float* __restrict__ bfc,
                                       float* __restrict__ xout,
                                       float* __restrict__ gout,
                                       const int row0, const int tid)
{
    if (tid < TILE * 4) {
        const int r = tid >> 2, q = tid & 3;
        const float* hrow = hbuf + r * HS + q * 32;
        const float* w0 = Wfc + q * 32;
        const float* w1 = Wfc + H + q * 32;
        float s0 = 0.f, s1 = 0.f;
#pragma unroll
        for (int i = 0; i < 32; i++) {
            const float h = hrow[i];
            s0 = fmaf(h, w0[i], s0);
            s1 = fmaf(h, w1[i], s1);
        }
        s0 += __shfl_xor(s0, 1, 64); s0 += __shfl_xor(s0, 2, 64);
        s1 += __shfl_xor(s1, 1, 64); s1 += __shfl_xor(s1, 2, 64);
        if (q == 0) {
            const float o0 = s0 + bfc[0];
            const float o1 = s1 + bfc[1];
            xout[r * 2 + 0] = o0;
            xout[r * 2 + 1] = o1;
            *(float2*)(gout + (size_t)(row0 + r) * 2) = make_float2(o0, o1);
        }
    }
}

__global__ __launch_bounds__(NTH, 2) void traj_kernel(
    const float* __restrict__ pos, const float* __restrict__ speed,
    const float* __restrict__ Wih_pe, const float* __restrict__ bih_pe, const float* __restrict__ bhh_pe,
    const float* __restrict__ Wih_se, const float* __restrict__ bih_se, const float* __restrict__ bhh_se,
    const float* __restrict__ ln_g, const float* __restrict__ ln_b,
    const float* __restrict__ Wih_sd, const float* __restrict__ bih_sd, const float* __restrict__ bhh_sd,
    const float* __restrict__ Wih_pd, const float* __restrict__ bih_pd, const float* __restrict__ bhh_pd,
    const float* __restrict__ Wfc, const float* __restrict__ bfc,
    const float4* __restrict__ wPacked, float* __restrict__ out)
{
    __shared__ __align__(16) float hA[TILE * HS];   // pos-chain h (-> hpo)
    __shared__ __align__(16) float hB[TILE * HS];   // speed-chain h (-> hds)
    __shared__ __align__(16) float tmp[TILE * HS];  // c LayerNorm staging
    __shared__ float xs[TILE * D];
    __shared__ float xp[TILE * D];

    const int tid = threadIdx.x;
    const int row0 = blockIdx.x * TILE;
    const int lane = tid & 63;
    const int wid = tid >> 6;
    const int rbase = wid * 8;   // this wave owns rows rbase..rbase+7 (wave-local recurrence)
    const int u0 = lane;
    const int u1 = lane + 64;

    float cA0[8], cA1[8], cB0[8], cB1[8];

    // ---- encoders ----
    encode_chain(pos, wPacked + 0 * H * H, Wih_pe, bih_pe, bhh_pe, hA, xp,
                 tid, row0, rbase, u0, u1, cA0, cA1);
    encode_chain(speed, wPacked + 1 * H * H, Wih_se, bih_se, bhh_se, hB, xs,
                 tid, row0, rbase, u0, u1, cB0, cB1);

    // ---- layernorms ----
    layernorm_lds(hA, ln_g, ln_b, tid);
    layernorm_lds(hB, ln_g, ln_b, tid);
    __syncthreads();

#pragma unroll
    for (int j = 0; j < 8; j++) { tmp[(rbase + j) * HS + u0] = cA0[j]; tmp[(rbase + j) * HS + u1] = cA1[j]; }
    __syncthreads();
    layernorm_lds(tmp, ln_g, ln_b, tid);
    __syncthreads();
#pragma unroll
    for (int j = 0; j < 8; j++) { cA0[j] = tmp[(rbase + j) * HS + u0]; cA1[j] = tmp[(rbase + j) * HS + u1]; }
    __syncthreads();
#pragma unroll
    for (int j = 0; j < 8; j++) { tmp[(rbase + j) * HS + u0] = cB0[j]; tmp[(rbase + j) * HS + u1] = cB1[j]; }
    __syncthreads();
    layernorm_lds(tmp, ln_g, ln_b, tid);
    __syncthreads();
#pragma unroll
    for (int j = 0; j < 8; j++) { cB0[j] = tmp[(rbase + j) * HS + u0]; cB1[j] = tmp[(rbase + j) * HS + u1]; }

    // decoder init: cds = LN(cpo)+LN(csp); cA stays as cpo; hB <- hds = hpo+hsp
    float cds0[8], cds1[8];
#pragma unroll
    for (int j = 0; j < 8; j++) { cds0[j] = cA0[j] + cB0[j]; cds1[j] = cA1[j] + cB1[j]; }

    for (int idx = tid; idx < TILE * H; idx += NTH) {
        const int r = idx >> 7, col = idx & (H - 1);
        hB[r * HS + col] += hA[r * HS + col];
    }
    if (tid < TILE * D) {
        xs[tid] = speed[(T_OBS - 1) * BATCH * D + row0 * D + tid];
        xp[tid] = pos[(T_OBS - 1) * BATCH * D + row0 * D + tid];
    }

    float4 sd_wd0_0, sd_wd1_0, sd_bs_0, sd_wd0_1, sd_wd1_1, sd_bs_1;
    float4 pd_wd0_0, pd_wd1_0, pd_bs_0, pd_wd0_1, pd_wd1_1, pd_bs_1;
    load_wx(Wih_sd, bih_sd, bhh_sd, u0, sd_wd0_0, sd_wd1_0, sd_bs_0);
    load_wx(Wih_sd, bih_sd, bhh_sd, u1, sd_wd0_1, sd_wd1_1, sd_bs_1);
    load_wx(Wih_pd, bih_pd, bhh_pd, u0, pd_wd0_0, pd_wd1_0, pd_bs_0);
    load_wx(Wih_pd, bih_pd, bhh_pd, u1, pd_wd0_1, pd_wd1_1, pd_bs_1);
    __syncthreads();

    const float4* wP_sd = wPacked + 2 * H * H;
    const float4* wP_pd = wPacked + 3 * H * H;
    float* pos_out = out;
    float* spd_out = out + (size_t)PRED * BATCH * D;

    // ---- decoder ----
    for (int t = 0; t < PRED; t++) {
        lstm_step(hB, xs, wP_sd, sd_wd0_0, sd_wd1_0, sd_bs_0,
                  sd_wd0_1, sd_wd1_1, sd_bs_1, rbase, u0, u1, cds0, cds1);
        fc_out(hB, Wfc, bfc, xs, spd_out + (size_t)t * BATCH * D, row0, tid);
        __syncthreads();
        lstm_step(hA, xp, wP_pd, pd_wd0_0, pd_wd1_0, pd_bs_0,
                  pd_wd0_1, pd_wd1_1, pd_bs_1, rbase, u0, u1, cA0, cA1);
        fc_out(hA, Wfc, bfc, xp, pos_out + (size_t)t * BATCH * D, row0, tid);
        __syncthreads();
    }
}

extern "C" void kernel_launch(void* const* d_in, const int* in_sizes, int n_in,
                              void* d_out, int out_size, void* d_ws, size_t ws_size,
                              hipStream_t stream)
{
    const float* pos    = (const float*)d_in[0];
    const float* speed  = (const float*)d_in[1];
    const float* Wih_pe = (const float*)d_in[2];
    const float* Whh_pe = (const float*)d_in[3];
    const float* bih_pe = (const float*)d_in[4];
    const float* bhh_pe = (const float*)d_in[5];
    const float* Wih_se = (const float*)d_in[6];
    const float* Whh_se = (const float*)d_in[7];
    const float* bih_se = (const float*)d_in[8];
    const float* bhh_se = (const float*)d_in[9];
    const float* ln_g   = (const float*)d_in[10];
    const float* ln_b   = (const float*)d_in[11];
    const float* Wih_sd = (const float*)d_in[12];
    const float* Whh_sd = (const float*)d_in[13];
    const float* bih_sd = (const float*)d_in[14];
    const float* bhh_sd = (const float*)d_in[15];
    const float* Wih_pd = (const float*)d_in[16];
    const float* Whh_pd = (const float*)d_in[17];
    const float* bih_pd = (const float*)d_in[18];
    const float* bhh_pd = (const float*)d_in[19];
    const float* Wfc    = (const float*)d_in[20];
    const float* bfc    = (const float*)d_in[21];

    float4* wPacked = (float4*)d_ws;   // 4 * 128*128 * 16B = 1 MiB

    pack_whh_kernel<<<(4 * H * H + 255) / 256, 256, 0, stream>>>(
        Whh_pe, Whh_se, Whh_sd, Whh_pd, wPacked);
    traj_kernel<<<BATCH / TILE, NTH, 0, stream>>>(
        pos, speed, Wih_pe, bih_pe, bhh_pe, Wih_se, bih_se, bhh_se,
        ln_g, ln_b, Wih_sd, bih_sd, bhh_sd, Wih_pd, bih_pd, bhh_pd,
        Wfc, bfc, wPacked, (float*)d_out);
}

// Round 2
// 1291.311 us; speedup vs baseline: 2.4570x; 2.4570x over previous
//
#include <hip/hip_runtime.h>

#define H 128
#define D 2
#define T_OBS 20
#define BATCH 16384
#define PRED 30
#define M 16          // batch rows per block
#define NTH 256       // 4 waves
#define HP 136        // padded bf16 h-row stride (+8 -> bank shift of 4, 2-way max)
#define FP 132        // padded f32 row stride
#define LN_EPS 1e-5f

typedef __attribute__((ext_vector_type(8))) short short8_t;
typedef __attribute__((ext_vector_type(4))) float float4_t;

__device__ __forceinline__ float fast_rcp(float x){ return __builtin_amdgcn_rcpf(x); }
__device__ __forceinline__ float sig_f(float x){ return fast_rcp(1.f + __expf(-x)); }
__device__ __forceinline__ float tanh_f(float x){ return 1.f - 2.f*fast_rcp(__expf(2.f*x)+1.f); }

__device__ __forceinline__ short f2bf(float f){      // RNE float->bf16
  union{float f; unsigned u;} v; v.f = f;
  unsigned r = (v.u + 0x7FFFu + ((v.u>>16)&1u)) >> 16;
  return (short)r;
}
__device__ __forceinline__ float bf2f(short s){
  union{float f; unsigned u;} v; v.u = ((unsigned)(unsigned short)s) << 16;
  return v.f;
}

// Per-phase constants held in registers.
// bw[g][ui][ks]: B-fragment for N-tile (gate g, unit-tile 2*wv+ui), K-slice ks.
struct PhaseConsts {
  short8_t bw[4][2][4];        // 128 VGPRs
  float bs[4][2], w0[4][2], w1[4][2];
};

__device__ __forceinline__ void load_phase(PhaseConsts& P, const float* __restrict__ Whh,
                                           const float* __restrict__ Wih,
                                           const float* __restrict__ bih,
                                           const float* __restrict__ bhh,
                                           int wv, int l15, int q){
#pragma unroll
  for(int g=0; g<4; g++)
#pragma unroll
    for(int ui=0; ui<2; ui++){
      const int u = 32*wv + 16*ui + l15;
      const int n = g*H + u;
      P.bs[g][ui] = bih[n] + bhh[n];
      P.w0[g][ui] = Wih[n*D + 0];
      P.w1[g][ui] = Wih[n*D + 1];
#pragma unroll
      for(int ks=0; ks<4; ks++){
        const float* p = Whh + (size_t)n*H + ks*32 + q*8;  // B[k][n]=Whh[n][k], k=32ks+8q+j
        float4 a = *(const float4*)p;
        float4 b = *(const float4*)(p+4);
        short8_t f;
        f[0]=f2bf(a.x); f[1]=f2bf(a.y); f[2]=f2bf(a.z); f[3]=f2bf(a.w);
        f[4]=f2bf(b.x); f[5]=f2bf(b.y); f[6]=f2bf(b.z); f[7]=f2bf(b.w);
        P.bw[g][ui][ks] = f;
      }
    }
}

// One LSTM cell step. Reads h from hsh[cur] (hi+lo planes), x from xsrc[16][2],
// writes new h (hi/lo bf16) to hsh[cur^1]. c state per-lane fp32. 1 barrier.
__device__ __forceinline__ void cell_step(short (*hsh)[2][M][HP], int cur,
                                          const float* __restrict__ xsrc,
                                          const PhaseConsts& P, float (&c)[2][4],
                                          int wv, int l15, int q){
  float4_t acc[4][2];
  float x0[4], x1[4];
#pragma unroll
  for(int r=0; r<4; r++){
    x0[r] = xsrc[(4*q+r)*2 + 0];
    x1[r] = xsrc[(4*q+r)*2 + 1];
  }
#pragma unroll
  for(int g=0; g<4; g++)
#pragma unroll
    for(int ui=0; ui<2; ui++)
#pragma unroll
      for(int r=0; r<4; r++)
        acc[g][ui][r] = fmaf(P.w1[g][ui], x1[r], fmaf(P.w0[g][ui], x0[r], P.bs[g][ui]));

#pragma unroll
  for(int ks=0; ks<4; ks++){
    const short8_t ahi = *(const short8_t*)&hsh[cur][0][l15][ks*32 + q*8];
    const short8_t alo = *(const short8_t*)&hsh[cur][1][l15][ks*32 + q*8];
#pragma unroll
    for(int g=0; g<4; g++)
#pragma unroll
      for(int ui=0; ui<2; ui++){
        acc[g][ui] = __builtin_amdgcn_mfma_f32_16x16x32_bf16(ahi, P.bw[g][ui][ks], acc[g][ui], 0,0,0);
        acc[g][ui] = __builtin_amdgcn_mfma_f32_16x16x32_bf16(alo, P.bw[g][ui][ks], acc[g][ui], 0,0,0);
      }
  }
  const int nxt = cur ^ 1;
#pragma unroll
  for(int ui=0; ui<2; ui++)
#pragma unroll
    for(int r=0; r<4; r++){
      const float iv = sig_f(acc[0][ui][r]);
      const float fv = sig_f(acc[1][ui][r]);
      const float gv = tanh_f(acc[2][ui][r]);
      const float ov = sig_f(acc[3][ui][r]);
      const float cc = fmaf(fv, c[ui][r], iv*gv);
      c[ui][r] = cc;
      const float hv = ov * tanh_f(cc);
      const short hi = f2bf(hv);
      const short lo = f2bf(hv - bf2f(hi));
      const int m = 4*q + r;                 // C-layout row
      const int u = 32*wv + 16*ui + l15;     // C-layout col = unit
      hsh[nxt][0][m][u] = hi;
      hsh[nxt][1][m][u] = lo;
    }
  __syncthreads();
}

// LayerNorm over 128 units for 16 rows; 16 threads/row, in-place safe.
__device__ __forceinline__ void layernorm16(const float (*src)[FP], float (*dst)[FP],
                                            const float* __restrict__ g,
                                            const float* __restrict__ b, int tid){
  const int m = tid >> 4, sub = tid & 15;
  float v[8];
  float s = 0.f, s2 = 0.f;
#pragma unroll
  for(int j=0;j<8;j++){ v[j] = src[m][sub*8+j]; s += v[j]; s2 = fmaf(v[j], v[j], s2); }
#pragma unroll
  for(int msk=1; msk<16; msk<<=1){ s += __shfl_xor(s, msk, 64); s2 += __shfl_xor(s2, msk, 64); }
  const float mean = s * (1.f/H);
  const float var  = s2 * (1.f/H) - mean*mean;
  const float inv  = rsqrtf(var + LN_EPS);
#pragma unroll
  for(int j=0;j<8;j++){
    const int u = sub*8+j;
    dst[m][u] = fmaf((v[j]-mean)*inv, g[u], b[u]);
  }
}

// cs = h @ Wfc^T + bfc from hi/lo planes; writes xbuf and global out.
__device__ __forceinline__ void fc_step(const short (*hb)[M][HP], const float (*wfc)[H],
                                        const float* __restrict__ bfcs, float (*xb)[D],
                                        float* __restrict__ gout, int row0, int tid){
  const int m = tid >> 4, d = (tid >> 3) & 1, ch = tid & 7;
  const short* hi = &hb[0][m][ch*16];
  const short* lo = &hb[1][m][ch*16];
  float s = 0.f;
#pragma unroll
  for(int j=0;j<16;j++) s = fmaf(bf2f(hi[j]) + bf2f(lo[j]), wfc[d][ch*16+j], s);
  s += __shfl_xor(s, 1, 64); s += __shfl_xor(s, 2, 64); s += __shfl_xor(s, 4, 64);
  if(ch == 0){
    const float vv = s + bfcs[d];
    xb[m][d] = vv;
    gout[(size_t)(row0+m)*D + d] = vv;
  }
}

__global__ __launch_bounds__(NTH, 2) void traj_kernel(
    const float* __restrict__ pos, const float* __restrict__ speed,
    const float* __restrict__ Wih_pe, const float* __restrict__ Whh_pe,
    const float* __restrict__ bih_pe, const float* __restrict__ bhh_pe,
    const float* __restrict__ Wih_se, const float* __restrict__ Whh_se,
    const float* __restrict__ bih_se, const float* __restrict__ bhh_se,
    const float* __restrict__ ln_g, const float* __restrict__ ln_b,
    const float* __restrict__ Wih_sd, const float* __restrict__ Whh_sd,
    const float* __restrict__ bih_sd, const float* __restrict__ bhh_sd,
    const float* __restrict__ Wih_pd, const float* __restrict__ Whh_pd,
    const float* __restrict__ bih_pd, const float* __restrict__ bhh_pd,
    const float* __restrict__ Wfc, const float* __restrict__ bfc,
    float* __restrict__ out)
{
  __shared__ __align__(16) short hsh[2][2][M][HP];   // [buf][hi/lo][m][u]
  __shared__ float tmpf[M][FP];
  __shared__ float hpoN[M][FP];
  __shared__ float cpoN[M][FP];
  __shared__ float seqx[2][T_OBS][M][D];
  __shared__ float xbuf[M][D];
  __shared__ float wfcs[D][H];
  __shared__ float bfcs[2];

  const int tid  = threadIdx.x;
  const int lane = tid & 63;
  const int wv   = tid >> 6;       // wave id 0..3 -> unit-tiles 2w, 2w+1
  const int q    = lane >> 4;      // quad
  const int l15  = lane & 15;
  const int row0 = blockIdx.x * M;

  // ---- stage inputs ----
  for(int idx = tid; idx < 2*T_OBS*M*D; idx += NTH){
    const int chain = idx / (T_OBS*M*D);
    const int rem   = idx % (T_OBS*M*D);
    const int t = rem >> 5, e = rem & 31;
    const float* src = chain ? speed : pos;
    seqx[chain][t][e>>1][e&1] = src[(size_t)t*BATCH*D + row0*D + e];
  }
  if(tid < D*H) wfcs[tid>>7][tid&127] = Wfc[tid];
  if(tid < 2)   bfcs[tid] = bfc[tid];
  { int* hz = (int*)&hsh[0][0][0][0];
    for(int idx = tid; idx < 2*2*M*HP/2; idx += NTH) hz[idx] = 0; }

  PhaseConsts P;
  float c[2][4];
  load_phase(P, Whh_pe, Wih_pe, bih_pe, bhh_pe, wv, l15, q);
#pragma unroll
  for(int ui=0;ui<2;ui++)
#pragma unroll
    for(int r=0;r<4;r++) c[ui][r] = 0.f;
  __syncthreads();

  // ---------- phase 1: pos encoder ----------
  int cur = 0;
  for(int t=0; t<T_OBS; t++){ cell_step(hsh, cur, &seqx[0][t][0][0], P, c, wv, l15, q); cur ^= 1; }
  for(int idx=tid; idx<M*H; idx+=NTH){
    const int m = idx>>7, u = idx&127;
    tmpf[m][u] = bf2f(hsh[cur][0][m][u]) + bf2f(hsh[cur][1][m][u]);
  }
  __syncthreads();
  layernorm16(tmpf, hpoN, ln_g, ln_b, tid);
  __syncthreads();
#pragma unroll
  for(int ui=0;ui<2;ui++)
#pragma unroll
    for(int r=0;r<4;r++) tmpf[4*q+r][32*wv+16*ui+l15] = c[ui][r];
  __syncthreads();
  layernorm16(tmpf, cpoN, ln_g, ln_b, tid);
  __syncthreads();

  // ---------- phase 2: speed encoder ----------
  load_phase(P, Whh_se, Wih_se, bih_se, bhh_se, wv, l15, q);
#pragma unroll
  for(int ui=0;ui<2;ui++)
#pragma unroll
    for(int r=0;r<4;r++) c[ui][r] = 0.f;
  for(int idx=tid; idx<M*H; idx+=NTH){
    const int m = idx>>7, u = idx&127;
    hsh[0][0][m][u] = 0; hsh[0][1][m][u] = 0;
  }
  cur = 0;
  __syncthreads();
  for(int t=0; t<T_OBS; t++){ cell_step(hsh, cur, &seqx[1][t][0][0], P, c, wv, l15, q); cur ^= 1; }
  for(int idx=tid; idx<M*H; idx+=NTH){
    const int m = idx>>7, u = idx&127;
    tmpf[m][u] = bf2f(hsh[cur][0][m][u]) + bf2f(hsh[cur][1][m][u]);
  }
  __syncthreads();
  layernorm16(tmpf, tmpf, ln_g, ln_b, tid);
  __syncthreads();
  // hds = LN(hsp) + LN(hpo) -> hsh[0]
  for(int idx=tid; idx<M*H; idx+=NTH){
    const int m = idx>>7, u = idx&127;
    const float v = tmpf[m][u] + hpoN[m][u];
    const short hi = f2bf(v);
    hsh[0][0][m][u] = hi;
    hsh[0][1][m][u] = f2bf(v - bf2f(hi));
  }
  __syncthreads();
  // cds = LN(csp) + LN(cpo)
#pragma unroll
  for(int ui=0;ui<2;ui++)
#pragma unroll
    for(int r=0;r<4;r++) tmpf[4*q+r][32*wv+16*ui+l15] = c[ui][r];
  __syncthreads();
  layernorm16(tmpf, tmpf, ln_g, ln_b, tid);
  __syncthreads();
#pragma unroll
  for(int ui=0;ui<2;ui++)
#pragma unroll
    for(int r=0;r<4;r++){
      const int m = 4*q+r, u = 32*wv+16*ui+l15;
      c[ui][r] = tmpf[m][u] + cpoN[m][u];
    }
  if(tid < M*D) xbuf[tid>>1][tid&1] = seqx[1][T_OBS-1][tid>>1][tid&1];
  load_phase(P, Whh_sd, Wih_sd, bih_sd, bhh_sd, wv, l15, q);
  __syncthreads();

  // ---------- phase 3: speed decoder ----------
  float* spd_out = out + (size_t)PRED*BATCH*D;
  cur = 0;
  for(int t=0; t<PRED; t++){
    cell_step(hsh, cur, &xbuf[0][0], P, c, wv, l15, q);
    fc_step(hsh[cur^1], wfcs, bfcs, xbuf, spd_out + (size_t)t*BATCH*D, row0, tid);
    __syncthreads();
    cur ^= 1;
  }

  // ---------- phase 4: pos decoder ----------
  for(int idx=tid; idx<M*H; idx+=NTH){
    const int m = idx>>7, u = idx&127;
    const float v = hpoN[m][u];
    const short hi = f2bf(v);
    hsh[0][0][m][u] = hi;
    hsh[0][1][m][u] = f2bf(v - bf2f(hi));
  }
#pragma unroll
  for(int ui=0;ui<2;ui++)
#pragma unroll
    for(int r=0;r<4;r++) c[ui][r] = cpoN[4*q+r][32*wv+16*ui+l15];
  if(tid < M*D) xbuf[tid>>1][tid&1] = seqx[0][T_OBS-1][tid>>1][tid&1];
  load_phase(P, Whh_pd, Wih_pd, bih_pd, bhh_pd, wv, l15, q);
  __syncthreads();
  cur = 0;
  for(int t=0; t<PRED; t++){
    cell_step(hsh, cur, &xbuf[0][0], P, c, wv, l15, q);
    fc_step(hsh[cur^1], wfcs, bfcs, xbuf, out + (size_t)t*BATCH*D, row0, tid);
    __syncthreads();
    cur ^= 1;
  }
}

extern "C" void kernel_launch(void* const* d_in, const int* in_sizes, int n_in,
                              void* d_out, int out_size, void* d_ws, size_t ws_size,
                              hipStream_t stream)
{
  const float* pos    = (const float*)d_in[0];
  const float* speed  = (const float*)d_in[1];
  const float* Wih_pe = (const float*)d_in[2];
  const float* Whh_pe = (const float*)d_in[3];
  const float* bih_pe = (const float*)d_in[4];
  const float* bhh_pe = (const float*)d_in[5];
  const float* Wih_se = (const float*)d_in[6];
  const float* Whh_se = (const float*)d_in[7];
  const float* bih_se = (const float*)d_in[8];
  const float* bhh_se = (const float*)d_in[9];
  const float* ln_g   = (const float*)d_in[10];
  const float* ln_b   = (const float*)d_in[11];
  const float* Wih_sd = (const float*)d_in[12];
  const float* Whh_sd = (const float*)d_in[13];
  const float* bih_sd = (const float*)d_in[14];
  const float* bhh_sd = (const float*)d_in[15];
  const float* Wih_pd = (const float*)d_in[16];
  const float* Whh_pd = (const float*)d_in[17];
  const float* bih_pd = (const float*)d_in[18];
  const float* bhh_pd = (const float*)d_in[19];
  const float* Wfc    = (const float*)d_in[20];
  const float* bfc    = (const float*)d_in[21];

  traj_kernel<<<BATCH/M, NTH, 0, stream>>>(
      pos, speed, Wih_pe, Whh_pe, bih_pe, bhh_pe,
      Wih_se, Whh_se, bih_se, bhh_se, ln_g, ln_b,
      Wih_sd, Whh_sd, bih_sd, bhh_sd, Wih_pd, Whh_pd, bih_pd, bhh_pd,
      Wfc, bfc, (float*)d_out);
}

// Round 3
// 794.809 us; speedup vs baseline: 3.9919x; 1.6247x over previous
//
#include <hip/hip_runtime.h>

#define H 128
#define D 2
#define T_OBS 20
#define BATCH 16384
#define PRED 30
#define M 16          // batch rows per block
#define NTH 512       // 8 waves; wave wv owns units 16*wv .. 16*wv+15 (all 4 gates)
#define HP 136        // padded bf16 h-row stride
#define FP 132        // padded f32 row stride
#define LN_EPS 1e-5f

typedef __attribute__((ext_vector_type(8))) short short8_t;
typedef __attribute__((ext_vector_type(4))) float float4_t;

__device__ __forceinline__ float fast_rcp(float x){ return __builtin_amdgcn_rcpf(x); }
__device__ __forceinline__ float sig_f(float x){ return fast_rcp(1.f + __expf(-x)); }
__device__ __forceinline__ float tanh_f(float x){ return 1.f - 2.f*fast_rcp(__expf(2.f*x)+1.f); }

__device__ __forceinline__ short f2bf(float f){      // RNE float->bf16
  union{float f; unsigned u;} v; v.f = f;
  unsigned r = (v.u + 0x7FFFu + ((v.u>>16)&1u)) >> 16;
  return (short)r;
}
__device__ __forceinline__ float bf2f(short s){
  union{float f; unsigned u;} v; v.u = ((unsigned)(unsigned short)s) << 16;
  return v.f;
}

// Per-phase per-wave constants: B-fragments for one 16-unit column group, 4 gates.
// bw[g][ks] = 4*4*4 = 64 VGPRs. Fits without spill.
struct PhaseConsts {
  short8_t bw[4][4];
  float bs[4], w0[4], w1[4];
};

__device__ __forceinline__ void load_phase(PhaseConsts& P, const float* __restrict__ Whh,
                                           const float* __restrict__ Wih,
                                           const float* __restrict__ bih,
                                           const float* __restrict__ bhh,
                                           int wv, int l15, int q){
#pragma unroll
  for(int g=0; g<4; g++){
    const int n = g*H + 16*wv + l15;
    P.bs[g] = bih[n] + bhh[n];
    P.w0[g] = Wih[n*D + 0];
    P.w1[g] = Wih[n*D + 1];
#pragma unroll
    for(int ks=0; ks<4; ks++){
      const float* p = Whh + (size_t)n*H + ks*32 + q*8;  // B[k][n]=Whh[n][k]
      float4 a = *(const float4*)p;
      float4 b = *(const float4*)(p+4);
      short8_t f;
      f[0]=f2bf(a.x); f[1]=f2bf(a.y); f[2]=f2bf(a.z); f[3]=f2bf(a.w);
      f[4]=f2bf(b.x); f[5]=f2bf(b.y); f[6]=f2bf(b.z); f[7]=f2bf(b.w);
      P.bw[g][ks] = f;
    }
  }
}

// One LSTM cell step. h read from hsh[cur] (hi+lo bf16 planes), x from xsrc[16][2],
// new h written to hsh[cur^1]. c per-lane fp32. One barrier.
__device__ __forceinline__ void cell_step(short (*hsh)[2][M][HP], int cur,
                                          const float* __restrict__ xsrc,
                                          const PhaseConsts& P, float (&c)[4],
                                          int wv, int l15, int q){
  float4_t acc[4];
  float x0[4], x1[4];
#pragma unroll
  for(int r=0; r<4; r++){
    x0[r] = xsrc[(4*q+r)*2 + 0];
    x1[r] = xsrc[(4*q+r)*2 + 1];
  }
#pragma unroll
  for(int g=0; g<4; g++)
#pragma unroll
    for(int r=0; r<4; r++)
      acc[g][r] = fmaf(P.w1[g], x1[r], fmaf(P.w0[g], x0[r], P.bs[g]));

#pragma unroll
  for(int ks=0; ks<4; ks++){
    const short8_t ahi = *(const short8_t*)&hsh[cur][0][l15][ks*32 + q*8];
    const short8_t alo = *(const short8_t*)&hsh[cur][1][l15][ks*32 + q*8];
#pragma unroll
    for(int g=0; g<4; g++){
      acc[g] = __builtin_amdgcn_mfma_f32_16x16x32_bf16(ahi, P.bw[g][ks], acc[g], 0,0,0);
      acc[g] = __builtin_amdgcn_mfma_f32_16x16x32_bf16(alo, P.bw[g][ks], acc[g], 0,0,0);
    }
  }
  const int nxt = cur ^ 1;
  const int u = 16*wv + l15;
#pragma unroll
  for(int r=0; r<4; r++){
    const float iv = sig_f(acc[0][r]);
    const float fv = sig_f(acc[1][r]);
    const float gv = tanh_f(acc[2][r]);
    const float ov = sig_f(acc[3][r]);
    const float cc = fmaf(fv, c[r], iv*gv);
    c[r] = cc;
    const float hv = ov * tanh_f(cc);
    const short hi = f2bf(hv);
    const short lo = f2bf(hv - bf2f(hi));
    const int m = 4*q + r;
    hsh[nxt][0][m][u] = hi;
    hsh[nxt][1][m][u] = lo;
  }
  __syncthreads();
}

// LayerNorm over 128 units for 16 rows; threads 0..255, 16 threads/row.
__device__ __forceinline__ void layernorm16(const float (*src)[FP], float (*dst)[FP],
                                            const float* __restrict__ g,
                                            const float* __restrict__ b, int tid){
  if(tid >= 256) return;
  const int m = tid >> 4, sub = tid & 15;
  float v[8];
  float s = 0.f, s2 = 0.f;
#pragma unroll
  for(int j=0;j<8;j++){ v[j] = src[m][sub*8+j]; s += v[j]; s2 = fmaf(v[j], v[j], s2); }
#pragma unroll
  for(int msk=1; msk<16; msk<<=1){ s += __shfl_xor(s, msk, 64); s2 += __shfl_xor(s2, msk, 64); }
  const float mean = s * (1.f/H);
  const float var  = s2 * (1.f/H) - mean*mean;
  const float inv  = rsqrtf(var + LN_EPS);
#pragma unroll
  for(int j=0;j<8;j++){
    const int u = sub*8+j;
    dst[m][u] = fmaf((v[j]-mean)*inv, g[u], b[u]);
  }
}

// cs = h @ Wfc^T + bfc from hi/lo planes; writes xbuf and global out. threads 0..255.
__device__ __forceinline__ void fc_step(const short (*hb)[M][HP], const float (*wfc)[H],
                                        const float* __restrict__ bfcs, float (*xb)[D],
                                        float* __restrict__ gout, int row0, int tid){
  if(tid >= 256) return;
  const int m = tid >> 4, d = (tid >> 3) & 1, ch = tid & 7;
  const short* hi = &hb[0][m][ch*16];
  const short* lo = &hb[1][m][ch*16];
  float s = 0.f;
#pragma unroll
  for(int j=0;j<16;j++) s = fmaf(bf2f(hi[j]) + bf2f(lo[j]), wfc[d][ch*16+j], s);
  s += __shfl_xor(s, 1, 64); s += __shfl_xor(s, 2, 64); s += __shfl_xor(s, 4, 64);
  if(ch == 0){
    const float vv = s + bfcs[d];
    xb[m][d] = vv;
    gout[(size_t)(row0+m)*D + d] = vv;
  }
}

__global__ __launch_bounds__(NTH, 2) void traj_kernel(
    const float* __restrict__ pos, const float* __restrict__ speed,
    const float* __restrict__ Wih_pe, const float* __restrict__ Whh_pe,
    const float* __restrict__ bih_pe, const float* __restrict__ bhh_pe,
    const float* __restrict__ Wih_se, const float* __restrict__ Whh_se,
    const float* __restrict__ bih_se, const float* __restrict__ bhh_se,
    const float* __restrict__ ln_g, const float* __restrict__ ln_b,
    const float* __restrict__ Wih_sd, const float* __restrict__ Whh_sd,
    const float* __restrict__ bih_sd, const float* __restrict__ bhh_sd,
    const float* __restrict__ Wih_pd, const float* __restrict__ Whh_pd,
    const float* __restrict__ bih_pd, const float* __restrict__ bhh_pd,
    const float* __restrict__ Wfc, const float* __restrict__ bfc,
    float* __restrict__ out)
{
  __shared__ __align__(16) short hsh[2][2][M][HP];   // [buf][hi/lo][m][u]
  __shared__ float tmpf[M][FP];
  __shared__ float hpoN[M][FP];
  __shared__ float cpoN[M][FP];
  __shared__ float seqx[2][T_OBS][M][D];
  __shared__ float xbuf[M][D];
  __shared__ float wfcs[D][H];
  __shared__ float bfcs[2];

  const int tid  = threadIdx.x;
  const int lane = tid & 63;
  const int wv   = tid >> 6;       // 0..7 -> unit group
  const int q    = lane >> 4;
  const int l15  = lane & 15;
  const int row0 = blockIdx.x * M;
  const int u    = 16*wv + l15;

  // ---- stage inputs ----
  for(int idx = tid; idx < 2*T_OBS*M*D; idx += NTH){
    const int chain = idx / (T_OBS*M*D);
    const int rem   = idx % (T_OBS*M*D);
    const int t = rem >> 5, e = rem & 31;
    const float* src = chain ? speed : pos;
    seqx[chain][t][e>>1][e&1] = src[(size_t)t*BATCH*D + row0*D + e];
  }
  if(tid < D*H) wfcs[tid>>7][tid&127] = Wfc[tid];
  if(tid < 2)   bfcs[tid] = bfc[tid];
  { int* hz = (int*)&hsh[0][0][0][0];                 // zero buf0 (both planes)
    for(int idx = tid; idx < 2*M*HP/2; idx += NTH) hz[idx] = 0; }

  PhaseConsts P;
  float c[4];
  load_phase(P, Whh_pe, Wih_pe, bih_pe, bhh_pe, wv, l15, q);
#pragma unroll
  for(int r=0;r<4;r++) c[r] = 0.f;
  __syncthreads();

  // ---------- phase 1: pos encoder ----------
  int cur = 0;
  for(int t=0; t<T_OBS; t++){ cell_step(hsh, cur, &seqx[0][t][0][0], P, c, wv, l15, q); cur ^= 1; }
  for(int idx=tid; idx<M*H; idx+=NTH){
    const int m = idx>>7, uu = idx&127;
    tmpf[m][uu] = bf2f(hsh[cur][0][m][uu]) + bf2f(hsh[cur][1][m][uu]);
  }
  __syncthreads();
  layernorm16(tmpf, hpoN, ln_g, ln_b, tid);
  __syncthreads();
#pragma unroll
  for(int r=0;r<4;r++) tmpf[4*q+r][u] = c[r];
  __syncthreads();
  layernorm16(tmpf, cpoN, ln_g, ln_b, tid);
  __syncthreads();

  // ---------- phase 2: speed encoder ----------
  load_phase(P, Whh_se, Wih_se, bih_se, bhh_se, wv, l15, q);
#pragma unroll
  for(int r=0;r<4;r++) c[r] = 0.f;
  for(int idx=tid; idx<M*H; idx+=NTH){
    const int m = idx>>7, uu = idx&127;
    hsh[0][0][m][uu] = 0; hsh[0][1][m][uu] = 0;
  }
  cur = 0;
  __syncthreads();
  for(int t=0; t<T_OBS; t++){ cell_step(hsh, cur, &seqx[1][t][0][0], P, c, wv, l15, q); cur ^= 1; }
  for(int idx=tid; idx<M*H; idx+=NTH){
    const int m = idx>>7, uu = idx&127;
    tmpf[m][uu] = bf2f(hsh[cur][0][m][uu]) + bf2f(hsh[cur][1][m][uu]);
  }
  __syncthreads();
  layernorm16(tmpf, tmpf, ln_g, ln_b, tid);
  __syncthreads();
  // hds = LN(hsp) + LN(hpo) -> hsh[0]
  for(int idx=tid; idx<M*H; idx+=NTH){
    const int m = idx>>7, uu = idx&127;
    const float v = tmpf[m][uu] + hpoN[m][uu];
    const short hi = f2bf(v);
    hsh[0][0][m][uu] = hi;
    hsh[0][1][m][uu] = f2bf(v - bf2f(hi));
  }
  __syncthreads();
  // cds = LN(csp) + LN(cpo)
#pragma unroll
  for(int r=0;r<4;r++) tmpf[4*q+r][u] = c[r];
  __syncthreads();
  layernorm16(tmpf, tmpf, ln_g, ln_b, tid);
  __syncthreads();
#pragma unroll
  for(int r=0;r<4;r++) c[r] = tmpf[4*q+r][u] + cpoN[4*q+r][u];
  if(tid < M*D) xbuf[tid>>1][tid&1] = seqx[1][T_OBS-1][tid>>1][tid&1];
  load_phase(P, Whh_sd, Wih_sd, bih_sd, bhh_sd, wv, l15, q);
  __syncthreads();

  // ---------- phase 3: speed decoder ----------
  float* spd_out = out + (size_t)PRED*BATCH*D;
  cur = 0;
  for(int t=0; t<PRED; t++){
    cell_step(hsh, cur, &xbuf[0][0], P, c, wv, l15, q);
    fc_step(hsh[cur^1], wfcs, bfcs, xbuf, spd_out + (size_t)t*BATCH*D, row0, tid);
    __syncthreads();
    cur ^= 1;
  }

  // ---------- phase 4: pos decoder ----------
  for(int idx=tid; idx<M*H; idx+=NTH){
    const int m = idx>>7, uu = idx&127;
    const float v = hpoN[m][uu];
    const short hi = f2bf(v);
    hsh[0][0][m][uu] = hi;
    hsh[0][1][m][uu] = f2bf(v - bf2f(hi));
  }
#pragma unroll
  for(int r=0;r<4;r++) c[r] = cpoN[4*q+r][u];
  if(tid < M*D) xbuf[tid>>1][tid&1] = seqx[0][T_OBS-1][tid>>1][tid&1];
  load_phase(P, Whh_pd, Wih_pd, bih_pd, bhh_pd, wv, l15, q);
  __syncthreads();
  cur = 0;
  for(int t=0; t<PRED; t++){
    cell_step(hsh, cur, &xbuf[0][0], P, c, wv, l15, q);
    fc_step(hsh[cur^1], wfcs, bfcs, xbuf, out + (size_t)t*BATCH*D, row0, tid);
    __syncthreads();
    cur ^= 1;
  }
}

extern "C" void kernel_launch(void* const* d_in, const int* in_sizes, int n_in,
                              void* d_out, int out_size, void* d_ws, size_t ws_size,
                              hipStream_t stream)
{
  const float* pos    = (const float*)d_in[0];
  const float* speed  = (const float*)d_in[1];
  const float* Wih_pe = (const float*)d_in[2];
  const float* Whh_pe = (const float*)d_in[3];
  const float* bih_pe = (const float*)d_in[4];
  const float* bhh_pe = (const float*)d_in[5];
  const float* Wih_se = (const float*)d_in[6];
  const float* Whh_se = (const float*)d_in[7];
  const float* bih_se = (const float*)d_in[8];
  const float* bhh_se = (const float*)d_in[9];
  const float* ln_g   = (const float*)d_in[10];
  const float* ln_b   = (const float*)d_in[11];
  const float* Wih_sd = (const float*)d_in[12];
  const float* Whh_sd = (const float*)d_in[13];
  const float* bih_sd = (const float*)d_in[14];
  const float* bhh_sd = (const float*)d_in[15];
  const float* Wih_pd = (const float*)d_in[16];
  const float* Whh_pd = (const float*)d_in[17];
  const float* bih_pd = (const float*)d_in[18];
  const float* bhh_pd = (const float*)d_in[19];
  const float* Wfc    = (const float*)d_in[20];
  const float* bfc    = (const float*)d_in[21];

  traj_kernel<<<BATCH/M, NTH, 0, stream>>>(
      pos, speed, Wih_pe, Whh_pe, bih_pe, bhh_pe,
      Wih_se, Whh_se, bih_se, bhh_se, ln_g, ln_b,
      Wih_sd, Whh_sd, bih_sd, bhh_sd, Wih_pd, Whh_pd, bih_pd, bhh_pd,
      Wfc, bfc, (float*)d_out);
}